// Round 11
// baseline (235.522 us; speedup 1.0000x reference)
//
#include <hip/hip_runtime.h>
#include <hip/hip_bf16.h>
#include <math.h>
#include <stdint.h>

// Problem constants (B=2, S=2048 -> T=4096 tokens)
#define TOKENS 4096
#define HDIM   768
#define FFDIM  1536
#define NEXP   8

typedef __attribute__((ext_vector_type(8))) short bf16x8;   // 8 bf16 = 4 VGPRs
typedef __attribute__((ext_vector_type(4))) float f32x4;    // MFMA accumulator
typedef __attribute__((ext_vector_type(4))) float fvec4;    // nt-load vector
typedef __attribute__((ext_vector_type(4))) unsigned short usvec4; // nt-store vector

// round-to-nearest-even f32 -> bf16 (bit pattern)
__device__ __forceinline__ unsigned short f2bf(float f) {
    union { float f; uint32_t u; } c; c.f = f;
    uint32_t u = c.u;
    uint32_t r = (u + 0x7FFFu + ((u >> 16) & 1u)) >> 16;
    return (unsigned short)r;
}

// async global->LDS, 16B per lane; LDS dest is wave-uniform base + lane*16
__device__ __forceinline__ void gload_lds16(const void* g, void* l) {
    __builtin_amdgcn_global_load_lds(
        (const __attribute__((address_space(1))) void*)g,
        (__attribute__((address_space(3))) void*)l, 16, 0, 0);
}

// cast one float4 -> ushort4 via clang ext_vector types (the nt builtins
// reject HIP_vector_type wrappers — r10 compile failure). NT load (weight
// source is a pure stream, never reused -> keep out of L2). NT store
// optional (wpj_bf is written DURING GEMM1; don't evict its B panels).
template<bool NTST>
__device__ __forceinline__ void cast4(const float* __restrict__ s,
                                      unsigned short* __restrict__ d, int i) {
    fvec4 v = __builtin_nontemporal_load((const fvec4*)s + i);
    usvec4 o;
    o.x = f2bf(v.x); o.y = f2bf(v.y); o.z = f2bf(v.z); o.w = f2bf(v.w);
    if constexpr (NTST) __builtin_nontemporal_store(o, (usvec4*)d + i);
    else                ((usvec4*)d)[i] = o;
}

// ---------------------------------------------------------------------------
// Dispatch 1: gating (blocks 0..1023) + wfc cast (blocks 1024..2047).
// Gating: one wave per token, fp32 logits (checked output!), top-2 softmax,
// NO atomics (r2: contended atomics serialized to 102us). Fused: bf16 cast
// of x, outp zeroing. Routing lists are derived by the GEMM1 dispatch's
// per-block SELF-SCAN (r10) — no build dispatch, no inter-block sync.
__global__ __launch_bounds__(256) void gating(
    const float* __restrict__ x, const float* __restrict__ gw,
    float* __restrict__ logits,
    int* __restrict__ tok_e, float* __restrict__ tok_g,
    unsigned short* __restrict__ x_bf, float* __restrict__ outp,
    const float* __restrict__ wfc, unsigned short* __restrict__ wfc_bf, int n4)
{
    if (blockIdx.x >= 1024) {
        // ---- wfc cast arm (1024 blocks): nt loads, normal stores
        int stride = 1024 * 256;
        for (int i = (int)(blockIdx.x - 1024) * 256 + threadIdx.x; i < n4; i += stride)
            cast4<false>(wfc, wfc_bf, i);
        return;
    }
    // zero outp: 786432 float4 over 1024 blocks = 3 per thread
    float4 zz = make_float4(0.f, 0.f, 0.f, 0.f);
#pragma unroll
    for (int j = 0; j < 3; j++)
        ((float4*)outp)[blockIdx.x * 768 + j * 256 + threadIdx.x] = zz;

    int t = blockIdx.x * 4 + (threadIdx.x >> 6);
    int lane = threadIdx.x & 63;
    const float4* xt = (const float4*)(x + (size_t)t * HDIM);   // 192 float4/token
    const float4* gw4 = (const float4*)gw;                      // [E][192]
    ushort4* xbt = (ushort4*)(x_bf + (size_t)t * HDIM);
    float acc[NEXP];
#pragma unroll
    for (int e = 0; e < NEXP; e++) acc[e] = 0.f;
#pragma unroll
    for (int it = 0; it < 3; it++) {
        int i = lane + it * 64;
        float4 xv = xt[i];
        ushort4 o;
        o.x = f2bf(xv.x); o.y = f2bf(xv.y); o.z = f2bf(xv.z); o.w = f2bf(xv.w);
        xbt[i] = o;
#pragma unroll
        for (int e = 0; e < NEXP; e++) {
            float4 wv = gw4[e * 192 + i];
            acc[e] += xv.x * wv.x + xv.y * wv.y + xv.z * wv.z + xv.w * wv.w;
        }
    }
#pragma unroll
    for (int e = 0; e < NEXP; e++) {
#pragma unroll
        for (int off = 32; off > 0; off >>= 1)
            acc[e] += __shfl_xor(acc[e], off);
    }
    if (lane == 0) {
        float4 l0 = make_float4(acc[0], acc[1], acc[2], acc[3]);
        float4 l1 = make_float4(acc[4], acc[5], acc[6], acc[7]);
        float4* lp = (float4*)(logits + (size_t)t * NEXP);
        lp[0] = l0; lp[1] = l1;
        int i0 = 0; float v0 = acc[0];
#pragma unroll
        for (int e = 1; e < NEXP; e++) if (acc[e] > v0) { v0 = acc[e]; i0 = e; }
        int i1 = -1; float v1 = -3.4e38f;
#pragma unroll
        for (int e = 0; e < NEXP; e++) if (e != i0 && acc[e] > v1) { v1 = acc[e]; i1 = e; }
        float g0 = 1.f / (1.f + expf(v1 - v0));   // softmax over top-2 (v0 >= v1)
        tok_e[t * 2] = i0; tok_e[t * 2 + 1] = i1;
        tok_g[t * 2] = g0; tok_g[t * 2 + 1] = 1.f - g0;
    }
}

// ---------------------------------------------------------------------------
// Routed GEMM (r11 = r10 with the nt-builtin types fixed). K-loops are
// byte-for-byte r8's proven ones. SELF-SCAN routing for GEMM1 — every GEMM
// block independently recomputes the deterministic routing from tok_e/tok_g
// (64KB, L2-hot, ~3-4us with 512 threads). ZERO inter-block communication
// (r9's spin scheme was withdrawn; this cannot deadlock: no waits, no flags).
//   Phase 1 (packed-u64 wave REDUCTION over tok_e): all 8 expert counts ->
//     n_e, ebase, rts, nfill, early-exit. Slot-0 block publishes counts[bkt]
//     for GEMM2 (next dispatch; kernel-boundary visibility).
//   Phase 2 (per work item; packed-u64 prefix SCAN): slot of every (t,k);
//     items of THIS bucket landing in rows [row0,row0+256) fill s_lst LDS
//     (slot order == global token order -> bit-identical to r8's lists).
//     The p==0 block also writes global entries/gates for GEMM2's epilogue.
//   GEMM1 (IS_FC,SCAN): TN=128, drain-0 single-buffer, ~50KB -> 3 blk/CU;
//     grid 768 + 512 wproj-cast blocks (nt load + nt store). A-gather rows
//     come from s_lst (LDS) instead of global entries.
//   GEMM2 (DBUF,!SCAN): TN=64, T4 counted-vmcnt dbuf (vmcnt(5), never 0
//     in-loop), 80KB -> 2 blk/CU, reads global counts/entries/gates. r5-proven.
// LDS rows 128B = 8x16B segs, XOR swizzle seg^(row&7): 0 bank conflicts
// (verified r6). bucket == expert (XCD-affine under round-robin dispatch).
template<int KD, int ND, int TN, int NCTP, int GG, bool IS_FC, bool DBUF, bool SCAN>
__global__ __launch_bounds__(512) void moe_gemm(
    const unsigned short* __restrict__ Asrc,
    const unsigned short* __restrict__ Bsrc,    // [E][ND][KD] (B^T form)
    int* __restrict__ counts,
    int* __restrict__ entries,
    float* __restrict__ gates,
    unsigned short* __restrict__ hmid,
    float* __restrict__ outp,
    const float* __restrict__ castS, unsigned short* __restrict__ castD, int castN4,
    const int* __restrict__ tok_e, const float* __restrict__ tok_g)
{
    if constexpr (IS_FC) {
        if (blockIdx.x >= GG) {     // ---- wproj cast arm (512 blocks x 512 thr)
            int stride = 512 * 512;
            for (int i = (int)(blockIdx.x - GG) * 512 + threadIdx.x; i < castN4; i += stride)
                cast4<true>(castS, castD, i);
            return;
        }
    }
    constexpr int BM = 256;
    constexpr int SLOTS = GG / 8;
    constexpr int AJ = TN / 32;        // col frags per wave (4 or 2)
    constexpr int CB = TN / 64;        // B staging calls per wave (2 or 1)
    constexpr int NV = 4 + CB;         // gload_lds per wave per stage
    int bkt  = blockIdx.x & 7;         // bucket == expert
    int slot = blockIdx.x >> 3;        // 0..SLOTS-1
    int tid = threadIdx.x;

    // scan scratch (GEMM1 only; size-1 stubs otherwise)
    __shared__ unsigned long long swlo[SCAN ? 8 : 1], swhi[SCAN ? 8 : 1];
    __shared__ int s_cnt[SCAN ? 8 : 1];
    __shared__ int s_lst[SCAN ? 256 : 1];

    int n_e, ebase;
    if constexpr (SCAN) {
        // ---- phase 1: expert counts via packed-u64 wave reduction ----
        int lane = tid & 63, wid = tid >> 6;
        unsigned long long clo = 0, chi = 0;
#pragma unroll
        for (int b = 0; b < 4; b++) {
            int4 ev = ((const int4*)tok_e)[tid * 4 + b];
            int e4[4] = {ev.x, ev.y, ev.z, ev.w};
#pragma unroll
            for (int j = 0; j < 4; j++) {
                unsigned long long one = 1ull << ((e4[j] & 3) * 16);
                if (e4[j] < 4) clo += one; else chi += one;
            }
        }
#pragma unroll
        for (int s = 1; s < 64; s <<= 1) {
            clo += __shfl_xor(clo, s);
            chi += __shfl_xor(chi, s);
        }
        if (lane == 0) { swlo[wid] = clo; swhi[wid] = chi; }
        __syncthreads();
        if (tid == 0) {
            unsigned long long rl = 0, rh = 0;
#pragma unroll
            for (int i = 0; i < 8; i++) { rl += swlo[i]; rh += swhi[i]; }
#pragma unroll
            for (int e = 0; e < 4; e++) {
                s_cnt[e]     = (int)((rl >> (e * 16)) & 0xFFFF);
                s_cnt[e + 4] = (int)((rh >> (e * 16)) & 0xFFFF);
            }
        }
        __syncthreads();
        n_e = s_cnt[bkt];
        if (slot == 0 && tid == 0) counts[bkt] = n_e;   // publish for GEMM2
        ebase = 0;
#pragma unroll
        for (int e = 0; e < NEXP; e++) if (e < bkt) ebase += s_cnt[e];
    } else {
        n_e = counts[bkt];
        ebase = 0;
#pragma unroll
        for (int e = 0; e < NEXP; e++) { int c = counts[e]; if (e < bkt) ebase += c; }
    }
    int rts = (n_e + BM - 1) >> 8;
    int nfill = rts * NCTP;
    if (slot >= nfill) return;     // counts already published; no entries lost
    const int* lst = entries + bkt * TOKENS;   // global list (GEMM2 path)

    int w = tid >> 6;          // wave 0..7
    int l = tid & 63;          // lane
    int sg = l & 7;
    int lr8 = l >> 3;          // row-within-8 staged by this lane
    int lo = l & 15;
    int q  = l >> 4;
    int wr = w >> 1, wc = w & 1;   // 4x2 wave grid: 64 rows x TN/2 cols each

    __shared__ __align__(16) unsigned short sA[(DBUF ? 2 : 1) * BM * 64];
    __shared__ __align__(16) unsigned short sB[(DBUF ? 2 : 1) * TN * 64];
    unsigned short* sA0 = sA;
    unsigned short* sA1 = sA + BM * 64;   // compile-time offsets (static alias)
    unsigned short* sB0 = sB;
    unsigned short* sB1 = sB + TN * 64;

    // fragment LDS offsets (item-independent)
    int aOff[4][2], bOff[AJ][2];
#pragma unroll
    for (int i = 0; i < 4; i++) {
        int m = wr * 64 + i * 16 + lo;
#pragma unroll
        for (int s = 0; s < 2; s++)
            aOff[i][s] = m * 64 + ((s * 4 + q) ^ (m & 7)) * 8;
    }
#pragma unroll
    for (int j = 0; j < AJ; j++) {
        int n = wc * (TN / 2) + j * 16 + lo;
#pragma unroll
        for (int s = 0; s < 2; s++)
            bOff[j][s] = n * 64 + ((s * 4 + q) ^ (n & 7)) * 8;
    }

    for (int p = slot; p < nfill; p += SLOTS) {   // backstop stride; 1 iter typical
        int ct   = p / rts;
        int r    = p - ct * rts;
        int row0 = r << 8;
        int n0 = ct * TN;

        if constexpr (SCAN) {
            // ---- phase 2: prefix scan; fill s_lst for [row0,row0+256);
            //      p==0 block also publishes global entries/gates for GEMM2.
            int lane = tid & 63, wid = tid >> 6;
            int eL[16]; float gL[16];
#pragma unroll
            for (int b = 0; b < 4; b++) {
                int4 ev = ((const int4*)tok_e)[tid * 4 + b];
                float4 gv = ((const float4*)tok_g)[tid * 4 + b];
                eL[b*4+0] = ev.x; eL[b*4+1] = ev.y; eL[b*4+2] = ev.z; eL[b*4+3] = ev.w;
                gL[b*4+0] = gv.x; gL[b*4+1] = gv.y; gL[b*4+2] = gv.z; gL[b*4+3] = gv.w;
            }
            unsigned long long clo = 0, chi = 0;
#pragma unroll
            for (int j = 0; j < 16; j++) {
                unsigned long long one = 1ull << ((eL[j] & 3) * 16);
                if (eL[j] < 4) clo += one; else chi += one;
            }
            unsigned long long ilo = clo, ihi = chi;
#pragma unroll
            for (int s = 1; s < 64; s <<= 1) {
                unsigned long long t1 = __shfl_up(ilo, s);
                unsigned long long t2 = __shfl_up(ihi, s);
                if (lane >= s) { ilo += t1; ihi += t2; }
            }
            __syncthreads();   // protect swlo reuse + s_lst WAR across p iters
            if (lane == 63) { swlo[wid] = ilo; swhi[wid] = ihi; }
            __syncthreads();
            if (tid == 0) {
                unsigned long long rl = 0, rh = 0;
#pragma unroll
                for (int i = 0; i < 8; i++) {
                    unsigned long long a = swlo[i], b2 = swhi[i];
                    swlo[i] = rl; swhi[i] = rh;   // exclusive wave prefix
                    rl += a; rh += b2;
                }
            }
            __syncthreads();
            unsigned long long rlo = swlo[wid] + (ilo - clo);
            unsigned long long rhi = swhi[wid] + (ihi - chi);
#pragma unroll
            for (int j = 0; j < 16; j++) {
                int e = eL[j];
                int sh = (e & 3) * 16;
                unsigned long long one = 1ull << sh;
                int sv;
                if (e < 4) { sv = (int)((rlo >> sh) & 0xFFFF); rlo += one; }
                else       { sv = (int)((rhi >> sh) & 0xFFFF); rhi += one; }
                if (e == bkt) {
                    int rel = sv - row0;
                    if ((unsigned)rel < 256u) s_lst[rel] = tid * 16 + j;  // = t*2+k
                    if (p == 0) {
                        entries[bkt * TOKENS + sv] = tid * 16 + j;
                        gates[bkt * TOKENS + sv]   = gL[j];
                    }
                }
            }
            __syncthreads();   // s_lst complete before staging addresses
        }

        // ---- staging addresses: rows are 128B (64 shorts), 8 segs of 16B.
        // A call covers 8 rows (64 lanes x 16B = 1KB). Global K-seg for
        // (row rr, LDS seg sg) is sg ^ (rr&7). Wave w stages A rows
        // [w*32, w*32+32) (4 calls) and B rows [w*(TN/8), ...) (CB calls).
        const unsigned short* Ag[4];
        int aLds[4];
#pragma unroll
        for (int c = 0; c < 4; c++) {
            int rr = w * 32 + c * 8 + lr8;       // tile row 0..255
            int gr = row0 + rr;
            int id = gr < n_e ? gr : n_e - 1;    // clamp (discarded in epilogue)
            size_t arow;
            if constexpr (IS_FC) arow = (size_t)(s_lst[id - row0] >> 1);  // LDS list
            else                 arow = (size_t)(ebase + id);
            Ag[c] = Asrc + arow * KD + (size_t)((sg ^ (rr & 7)) * 8);
            aLds[c] = (w * 32 + c * 8) * 64;     // wave-uniform chunk base
        }
        const unsigned short* Bg[CB];
        int bLds[CB];
#pragma unroll
        for (int c = 0; c < CB; c++) {
            int rr = w * (TN / 8) + c * 8 + lr8; // tile row 0..TN-1
            Bg[c] = Bsrc + ((size_t)bkt * ND + n0 + rr) * KD + (size_t)((sg ^ (rr & 7)) * 8);
            bLds[c] = (w * (TN / 8) + c * 8) * 64;
        }

        f32x4 acc[4][AJ];
#pragma unroll
        for (int i = 0; i < 4; i++)
#pragma unroll
            for (int j = 0; j < AJ; j++) acc[i][j] = (f32x4){0.f, 0.f, 0.f, 0.f};

        auto stage = [&](unsigned short* SA, unsigned short* SB, int k0) {
#pragma unroll
            for (int c = 0; c < 4; c++) gload_lds16(Ag[c] + k0, SA + aLds[c]);
#pragma unroll
            for (int c = 0; c < CB; c++) gload_lds16(Bg[c] + k0, SB + bLds[c]);
        };
        auto compute = [&](const unsigned short* SA, const unsigned short* SB) {
#pragma unroll
            for (int s = 0; s < 2; s++) {
                bf16x8 a[4], b[AJ];
#pragma unroll
                for (int i = 0; i < 4; i++) a[i] = *(const bf16x8*)(SA + aOff[i][s]);
#pragma unroll
                for (int j = 0; j < AJ; j++) b[j] = *(const bf16x8*)(SB + bOff[j][s]);
#pragma unroll
                for (int i = 0; i < 4; i++)
#pragma unroll
                    for (int j = 0; j < AJ; j++)
                        acc[i][j] = __builtin_amdgcn_mfma_f32_16x16x32_bf16(a[i], b[j], acc[i][j], 0, 0, 0);
            }
        };

        if constexpr (!DBUF) {
            // single-buffer, drain-0 __syncthreads loop (r5 control, 51.2us)
            for (int k0 = 0; k0 < KD; k0 += 64) {
                stage(sA0, sB0, k0);
                __syncthreads();                // drains vmcnt (compiler-inserted)
                compute(sA0, sB0);
                __syncthreads();                // protect LDS before next staging
            }
        } else {
            // T4 counted-vmcnt double-buffer, raw barriers; vmcnt(NV) retires
            // the older buffer's loads while the newest NV stay in flight.
#define WAITN asm volatile("s_waitcnt vmcnt(%0)" :: "n"(NV) : "memory")
#define WAIT0 asm volatile("s_waitcnt vmcnt(0)" ::: "memory")
            stage(sA0, sB0, 0);
            for (int k0 = 0; k0 < KD; k0 += 128) {   // KD/128 = 12 iters
                stage(sA1, sB1, k0 + 64);
                WAITN;
                __builtin_amdgcn_s_barrier();
                __builtin_amdgcn_s_setprio(1);
                compute(sA0, sB0);
                __builtin_amdgcn_s_setprio(0);
                __builtin_amdgcn_s_barrier();
                if (k0 + 128 < KD) {
                    stage(sA0, sB0, k0 + 128);
                    WAITN;
                } else {
                    WAIT0;
                }
                __builtin_amdgcn_s_barrier();
                __builtin_amdgcn_s_setprio(1);
                compute(sA1, sB1);
                __builtin_amdgcn_s_setprio(0);
                __builtin_amdgcn_s_barrier();
            }
#undef WAITN
#undef WAIT0
        }

        // ---- epilogue (D: col=lo, row=q*4+rr)
#pragma unroll
        for (int i = 0; i < 4; i++) {
            int rowB = row0 + wr * 64 + i * 16 + q * 4;
#pragma unroll
            for (int rr = 0; rr < 4; rr++) {
                int orow = rowB + rr;
                if (orow < n_e) {
                    if (IS_FC) {
                        size_t hrow = (size_t)(ebase + orow);
#pragma unroll
                        for (int j = 0; j < AJ; j++) {
                            float v = acc[i][j][rr];
                            v = 0.5f * v * (1.f + erff(v * 0.70710678118654752f));  // exact gelu
                            hmid[hrow * ND + n0 + wc * (TN / 2) + j * 16 + lo] = f2bf(v);
                        }
                    } else {
                        int token = lst[orow] >> 1;
                        float g = gates[bkt * TOKENS + orow];
#pragma unroll
                        for (int j = 0; j < AJ; j++) {
                            atomicAdd(&outp[(size_t)token * ND + n0 + wc * (TN / 2) + j * 16 + lo],
                                      acc[i][j][rr] * g);
                        }
                    }
                }
            }
        }
    }
}

// ---------------------------------------------------------------------------
extern "C" void kernel_launch(void* const* d_in, const int* in_sizes, int n_in,
                              void* d_out, int out_size, void* d_ws, size_t ws_size,
                              hipStream_t stream) {
    const float* x     = (const float*)d_in[0];   // [T, H]
    const float* gw    = (const float*)d_in[1];   // [E, H]
    const float* wfc   = (const float*)d_in[2];   // [E, FF, H]
    const float* wproj = (const float*)d_in[3];   // [E, H, FF]
    float* outp   = (float*)d_out;                       // [T*H]
    float* logits = outp + (size_t)TOKENS * HDIM;        // [T*E]

    char* ws = (char*)d_ws;
    int*   counts  = (int*)ws;                            // 8 ints
    size_t off = 256;
    int*   entries = (int*)(ws + off);                    // [E][T]
    float* gates   = (float*)(ws + off + NEXP * TOKENS * 4);
    off += 2ull * NEXP * TOKENS * 4;
    int*   tok_e   = (int*)(ws + off);   off += (size_t)TOKENS * 2 * 4;
    float* tok_g   = (float*)(ws + off); off += (size_t)TOKENS * 2 * 4;
    unsigned short* x_bf   = (unsigned short*)(ws + off); off += (size_t)TOKENS * HDIM * 2;
    unsigned short* wfc_bf = (unsigned short*)(ws + off); off += (size_t)NEXP * FFDIM * HDIM * 2;
    unsigned short* wpj_bf = (unsigned short*)(ws + off); off += (size_t)NEXP * HDIM * FFDIM * 2;
    unsigned short* hmid   = (unsigned short*)(ws + off);        // [2T][FF] bf16, slot-compacted

    gating<<<2048, 256, 0, stream>>>(x, gw, logits, tok_e, tok_g, x_bf, outp,
                                     wfc, wfc_bf, NEXP * FFDIM * HDIM / 4);
    moe_gemm<HDIM, FFDIM, 128, FFDIM / 128, 768, true,  false, true>
        <<<768 + 512, 512, 0, stream>>>(
        x_bf, wfc_bf, counts, entries, gates, hmid, outp,
        wproj, wpj_bf, NEXP * HDIM * FFDIM / 4,
        tok_e, tok_g);
    moe_gemm<FFDIM, HDIM, 64,  HDIM / 64,   512, false, true, false>
        <<<512, 512, 0, stream>>>(
        hmid, wpj_bf, counts, entries, gates, hmid, outp,
        nullptr, nullptr, 0,
        nullptr, nullptr);
}